// Round 3
// baseline (214.684 us; speedup 1.0000x reference)
//
#include <hip/hip_runtime.h>
#include <hip/hip_bf16.h>

// HyperbolicMapper: LayerNorm -> spectral-norm linear (K=16) -> scale -> Poincare expmap0
// N=65536, D=4096, K=16. Memory-bound on reading x (1 GiB fp32).
// Roofline: ~1.078 GB / ~6.4 TB/s ~= 170 us.
//
// kk-slot remap (R2): col(s,lc,j) = s*32 + lc*4 + (j&3) + (j>>2)*16.
// Makes each x-load instruction cover 16 rows x contiguous 64 B (4x fewer
// TA segments than the R0 mapping). A-frag and B-frag (gwb layout) agree.

#define ND 4096
#define NK 16
#define NROWS 65536

using f32x4  = __attribute__((ext_vector_type(4))) float;
using bf16x8 = __attribute__((ext_vector_type(8))) short;

// workspace byte offsets
#define GWB_OFF  0u        // ushort[ND*NK] = 128 KB, gamma*W bf16, B-frag layout (remapped)
#define T_OFF    131072u   // float[ND]      : t = W^T u
#define PART_OFF 147456u   // float[16*33]   : per-block partials (nt2, G[16], B[16])
#define SC_OFF   149568u   // float[33]      : coef, G[16], B[16]

__device__ __forceinline__ unsigned short f2bf(float f) {
    union { __hip_bfloat16 h; unsigned short u; } cv;
    cv.h = __float2bfloat16(f);
    return cv.u;
}

// ---------------- prep A: per-column work over W (16 blocks x 256 thr) ----------------
// thread <-> one column d. Computes t[d]=sum_k W[k][d]*u[k], writes gamma*W as bf16 in
// the REMAPPED B-fragment layout, and block-reduces partials of nt2, G[k], B[k].
__global__ __launch_bounds__(256) void prep_a(
    const float* __restrict__ W, const float* __restrict__ gamma,
    const float* __restrict__ beta, const float* __restrict__ u,
    float* __restrict__ ws_t, unsigned short* __restrict__ ws_gwb,
    float* __restrict__ ws_part)
{
    const int d = blockIdx.x * 256 + threadIdx.x;
    float uu[NK];
#pragma unroll
    for (int k = 0; k < NK; ++k) uu[k] = u[k];
    const float g = gamma[d], b = beta[d];
    float w[NK];
#pragma unroll
    for (int k = 0; k < NK; ++k) w[k] = W[k * ND + d];
    float t = 0.f;
#pragma unroll
    for (int k = 0; k < NK; ++k) t = fmaf(w[k], uu[k], t);
    ws_t[d] = t;

    // remapped B-frag layout: d -> (s, lc, j); slot = s*512 + lc*128 + k*8 + j
    const int s  = d >> 5;
    const int wq = d & 31;
    const int lc = (wq >> 2) & 3;
    const int j  = (wq & 3) | ((wq >> 4) << 2);
    const int base = s * 512 + lc * 128 + j;
#pragma unroll
    for (int k = 0; k < NK; ++k) ws_gwb[base + k * 8] = f2bf(g * w[k]);

    __shared__ float red[256][34];
    red[threadIdx.x][0] = t * t;
#pragma unroll
    for (int k = 0; k < NK; ++k) {
        red[threadIdx.x][1 + k]  = g * w[k];
        red[threadIdx.x][17 + k] = b * w[k];
    }
    __syncthreads();
    for (int off = 128; off > 0; off >>= 1) {
        if (threadIdx.x < off)
            for (int v = 0; v < 33; ++v)
                red[threadIdx.x][v] += red[threadIdx.x + off][v];
        __syncthreads();
    }
    if (threadIdx.x < 33) ws_part[blockIdx.x * 33 + threadIdx.x] = red[0][threadIdx.x];
}

// ---------------- prep B: sigma + scalars (1 block x 256 thr) ----------------
__global__ __launch_bounds__(256) void prep_b(
    const float* __restrict__ W, const float* __restrict__ ws_t,
    const float* __restrict__ ws_part, const float* __restrict__ log_scale,
    float* __restrict__ sc)
{
    __shared__ float tot[33];
    __shared__ float red[256][17];
    const int tid = threadIdx.x;
    if (tid < 33) {
        float s = 0.f;
        for (int b = 0; b < 16; ++b) s += ws_part[b * 33 + tid];
        tot[tid] = s;
    }
    __syncthreads();
    const float inv_nt = 1.0f / (sqrtf(tot[0]) + 1e-12f);
    float sp[NK];
#pragma unroll
    for (int k = 0; k < NK; ++k) sp[k] = 0.f;
    for (int jj = 0; jj < 16; ++jj) {
        const int d = tid * 16 + jj;
        const float vd = ws_t[d] * inv_nt;
#pragma unroll
        for (int k = 0; k < NK; ++k) sp[k] = fmaf(W[k * ND + d], vd, sp[k]);
    }
#pragma unroll
    for (int k = 0; k < NK; ++k) red[tid][k] = sp[k];
    __syncthreads();
    for (int off = 128; off > 0; off >>= 1) {
        if (tid < off)
            for (int v = 0; v < NK; ++v) red[tid][v] += red[tid + off][v];
        __syncthreads();
    }
    if (tid == 0) {
        float ns2 = 0.f;
        for (int k = 0; k < NK; ++k) ns2 += red[0][k] * red[0][k];
        const float sigma = ns2 / (sqrtf(ns2) + 1e-12f);
        const float scale = 0.5f / (1.0f + expf(-log_scale[0]));  // sigmoid*0.5
        sc[0] = scale / sigma;
        for (int k = 0; k < NK; ++k) { sc[1 + k] = tot[1 + k]; sc[17 + k] = tot[17 + k]; }
    }
}

// ---------------- main: one pass over x, MFMA 16x16x32 bf16 ----------------
// 256 blocks x 1024 threads; 16 waves/block; wave <-> one 16-row tile.
// A-frag (remapped): lane l (n=l&15, lc=l>>4), step s:
//   xa = x[n][s*32 + lc*4 .. +3]   -> regs j=0..3
//   xb = x[n][s*32 + 16 + lc*4 ..] -> regs j=4..7
//   => per xa instruction the 4 same-row lanes cover contiguous 64 B.
// B-frag: gwb staged in LDS, read at ushort offset s*512 + lane*8 (linear 1 KB/wave).
// C: col = lane&15 (k), row = (lane>>4)*4 + reg  [m89-verified].
__global__ __launch_bounds__(1024, 4) void hyp_main(
    const float* __restrict__ x, const unsigned short* __restrict__ gwb_g,
    const float* __restrict__ sc, float* __restrict__ out)
{
    __shared__ unsigned short gwb[ND * NK];  // 128 KB

    const int lane = threadIdx.x & 63;
    const int wid  = threadIdx.x >> 6;
    const int tile = (blockIdx.x << 4) + wid;   // 0..4095, one per wave
    const int lr = lane & 15;                   // A-row within tile / C-col (k)
    const int lc = lane >> 4;                   // lane group

    const float* xp = x + (size_t)(tile * 16 + lr) * ND + lc * 4;
    const unsigned short* lp = gwb + lane * 8;  // + s*512 ushorts per step

    // issue step-0 x loads BEFORE the LDS staging so HBM starts immediately
    f32x4 xa = *(const f32x4*)(xp);
    f32x4 xb = *(const f32x4*)(xp + 16);

    {
        const uint4* src = (const uint4*)gwb_g;
        uint4* dst = (uint4*)gwb;
#pragma unroll
        for (int i = 0; i < 8; ++i)
            dst[threadIdx.x + i * 1024] = src[threadIdx.x + i * 1024];
    }
    __syncthreads();

    // epilogue scalars: issue early, used late
    const float coef = sc[0];
    const float gk = sc[1 + lr];   // G[k], k = lane&15 = C-col
    const float bk = sc[17 + lr];  // B[k]

    f32x4 acc = {0.f, 0.f, 0.f, 0.f};
    float s1 = 0.f, s2 = 0.f;

#define PROCESS(XA, XB, SS) do {                                          \
        bf16x8 afrag;                                                     \
        afrag[0] = (short)f2bf(XA[0]); afrag[1] = (short)f2bf(XA[1]);     \
        afrag[2] = (short)f2bf(XA[2]); afrag[3] = (short)f2bf(XA[3]);     \
        afrag[4] = (short)f2bf(XB[0]); afrag[5] = (short)f2bf(XB[1]);     \
        afrag[6] = (short)f2bf(XB[2]); afrag[7] = (short)f2bf(XB[3]);     \
        s1 += ((XA[0] + XA[1]) + (XA[2] + XA[3]))                         \
            + ((XB[0] + XB[1]) + (XB[2] + XB[3]));                        \
        s2 = fmaf(XA[0], XA[0], s2); s2 = fmaf(XA[1], XA[1], s2);         \
        s2 = fmaf(XA[2], XA[2], s2); s2 = fmaf(XA[3], XA[3], s2);         \
        s2 = fmaf(XB[0], XB[0], s2); s2 = fmaf(XB[1], XB[1], s2);         \
        s2 = fmaf(XB[2], XB[2], s2); s2 = fmaf(XB[3], XB[3], s2);         \
        bf16x8 bfrag = *(const bf16x8*)(lp + (SS) * 512);                 \
        acc = __builtin_amdgcn_mfma_f32_16x16x32_bf16(afrag, bfrag, acc, 0, 0, 0); \
    } while (0)

    // rotated software-prefetch: load step s+1 while processing step s
#pragma unroll 4
    for (int s = 0; s < 127; ++s) {
        f32x4 na = *(const f32x4*)(xp + (s + 1) * 32);
        f32x4 nb = *(const f32x4*)(xp + (s + 1) * 32 + 16);
        PROCESS(xa, xb, s);
        xa = na; xb = nb;
    }
    PROCESS(xa, xb, 127);
#undef PROCESS

    // S1/S2 for row lr: reduce across the 4 lanes {l, l^16, l^32, l^48}
    s1 += __shfl_xor(s1, 16); s1 += __shfl_xor(s1, 32);
    s2 += __shfl_xor(s2, 16); s2 += __shfl_xor(s2, 32);
    const float mean = s1 * (1.0f / ND);
    const float var  = s2 * (1.0f / ND) - mean * mean;
    const float rstd = rsqrtf(var + 1e-5f);

    float vout[4];
#pragma unroll
    for (int j = 0; j < 4; ++j) {
        const int r = lc * 4 + j;              // C-row within tile
        const float m_r  = __shfl(mean, r);    // stats live in lane r (r<16)
        const float rs_r = __shfl(rstd, r);
        vout[j] = coef * (fmaf(-m_r, gk, acc[j]) * rs_r + bk);
    }

    // row-norm over k: reduce across the 16 lanes sharing lc (xor masks 1,2,4,8)
    float nsq[4];
#pragma unroll
    for (int j = 0; j < 4; ++j) nsq[j] = vout[j] * vout[j];
#pragma unroll
    for (int m = 1; m < 16; m <<= 1) {
#pragma unroll
        for (int j = 0; j < 4; ++j) nsq[j] += __shfl_xor(nsq[j], m);
    }

#pragma unroll
    for (int j = 0; j < 4; ++j) {
        float nv = sqrtf(nsq[j]);
        nv = fmaxf(nv, 1e-15f);
        const float fac = tanhf(nv) / nv;
        out[(size_t)(tile * 16 + lc * 4 + j) * NK + lr] = vout[j] * fac;
    }
}

extern "C" void kernel_launch(void* const* d_in, const int* in_sizes, int n_in,
                              void* d_out, int out_size, void* d_ws, size_t ws_size,
                              hipStream_t stream) {
    const float* x     = (const float*)d_in[0];
    const float* gamma = (const float*)d_in[1];
    const float* beta  = (const float*)d_in[2];
    const float* W     = (const float*)d_in[3];
    const float* u     = (const float*)d_in[4];
    const float* ls    = (const float*)d_in[5];

    char* ws = (char*)d_ws;
    unsigned short* ws_gwb = (unsigned short*)(ws + GWB_OFF);
    float* ws_t    = (float*)(ws + T_OFF);
    float* ws_part = (float*)(ws + PART_OFF);
    float* sc      = (float*)(ws + SC_OFF);
    float* out     = (float*)d_out;

    prep_a<<<16, 256, 0, stream>>>(W, gamma, beta, u, ws_t, ws_gwb, ws_part);
    prep_b<<<1, 256, 0, stream>>>(W, ws_t, ws_part, ls, sc);
    hyp_main<<<256, 1024, 0, stream>>>(x, ws_gwb, sc, out);
}

// Round 4
// 203.094 us; speedup vs baseline: 1.0571x; 1.0571x over previous
//
#include <hip/hip_runtime.h>
#include <hip/hip_bf16.h>

// HyperbolicMapper: LayerNorm -> spectral-norm linear (K=16) -> scale -> Poincare expmap0
// N=65536, D=4096, K=16. Memory-bound on reading x (1 GiB fp32).
// R3: per-wave column rotation (start = (tile*53)&127) to decorrelate the
// instantaneous HBM address mix across waves (16 KB row stride aliases the
// channel interleave; all-waves-at-column-0 congests a channel subset).
// Sums/MFMA accumulation are column-order-invariant, so rotation is free.

#define ND 4096
#define NK 16
#define NROWS 65536

using f32x4  = __attribute__((ext_vector_type(4))) float;
using bf16x8 = __attribute__((ext_vector_type(8))) short;

// workspace byte offsets
#define GWB_OFF  0u        // ushort[ND*NK] = 128 KB, gamma*W bf16, B-frag layout (remapped)
#define T_OFF    131072u   // float[ND]      : t = W^T u
#define PART_OFF 147456u   // float[16*33]   : per-block partials (nt2, G[16], B[16])
#define SC_OFF   149568u   // float[33]      : coef, G[16], B[16]

__device__ __forceinline__ unsigned short f2bf(float f) {
    union { __hip_bfloat16 h; unsigned short u; } cv;
    cv.h = __float2bfloat16(f);
    return cv.u;
}

// ---------------- prep A: per-column work over W (16 blocks x 256 thr) ----------------
__global__ __launch_bounds__(256) void prep_a(
    const float* __restrict__ W, const float* __restrict__ gamma,
    const float* __restrict__ beta, const float* __restrict__ u,
    float* __restrict__ ws_t, unsigned short* __restrict__ ws_gwb,
    float* __restrict__ ws_part)
{
    const int d = blockIdx.x * 256 + threadIdx.x;
    float uu[NK];
#pragma unroll
    for (int k = 0; k < NK; ++k) uu[k] = u[k];
    const float g = gamma[d], b = beta[d];
    float w[NK];
#pragma unroll
    for (int k = 0; k < NK; ++k) w[k] = W[k * ND + d];
    float t = 0.f;
#pragma unroll
    for (int k = 0; k < NK; ++k) t = fmaf(w[k], uu[k], t);
    ws_t[d] = t;

    // remapped B-frag layout: d -> (s, lc, j); slot = s*512 + lc*128 + k*8 + j
    const int s  = d >> 5;
    const int wq = d & 31;
    const int lc = (wq >> 2) & 3;
    const int j  = (wq & 3) | ((wq >> 4) << 2);
    const int base = s * 512 + lc * 128 + j;
#pragma unroll
    for (int k = 0; k < NK; ++k) ws_gwb[base + k * 8] = f2bf(g * w[k]);

    __shared__ float red[256][34];
    red[threadIdx.x][0] = t * t;
#pragma unroll
    for (int k = 0; k < NK; ++k) {
        red[threadIdx.x][1 + k]  = g * w[k];
        red[threadIdx.x][17 + k] = b * w[k];
    }
    __syncthreads();
    for (int off = 128; off > 0; off >>= 1) {
        if (threadIdx.x < off)
            for (int v = 0; v < 33; ++v)
                red[threadIdx.x][v] += red[threadIdx.x + off][v];
        __syncthreads();
    }
    if (threadIdx.x < 33) ws_part[blockIdx.x * 33 + threadIdx.x] = red[0][threadIdx.x];
}

// ---------------- prep B: sigma + scalars (1 block x 256 thr) ----------------
__global__ __launch_bounds__(256) void prep_b(
    const float* __restrict__ W, const float* __restrict__ ws_t,
    const float* __restrict__ ws_part, const float* __restrict__ log_scale,
    float* __restrict__ sc)
{
    __shared__ float tot[33];
    __shared__ float red[256][17];
    const int tid = threadIdx.x;
    if (tid < 33) {
        float s = 0.f;
        for (int b = 0; b < 16; ++b) s += ws_part[b * 33 + tid];
        tot[tid] = s;
    }
    __syncthreads();
    const float inv_nt = 1.0f / (sqrtf(tot[0]) + 1e-12f);
    float sp[NK];
#pragma unroll
    for (int k = 0; k < NK; ++k) sp[k] = 0.f;
    for (int jj = 0; jj < 16; ++jj) {
        const int d = tid * 16 + jj;
        const float vd = ws_t[d] * inv_nt;
#pragma unroll
        for (int k = 0; k < NK; ++k) sp[k] = fmaf(W[k * ND + d], vd, sp[k]);
    }
#pragma unroll
    for (int k = 0; k < NK; ++k) red[tid][k] = sp[k];
    __syncthreads();
    for (int off = 128; off > 0; off >>= 1) {
        if (tid < off)
            for (int v = 0; v < NK; ++v) red[tid][v] += red[tid + off][v];
        __syncthreads();
    }
    if (tid == 0) {
        float ns2 = 0.f;
        for (int k = 0; k < NK; ++k) ns2 += red[0][k] * red[0][k];
        const float sigma = ns2 / (sqrtf(ns2) + 1e-12f);
        const float scale = 0.5f / (1.0f + expf(-log_scale[0]));  // sigmoid*0.5
        sc[0] = scale / sigma;
        for (int k = 0; k < NK; ++k) { sc[1 + k] = tot[1 + k]; sc[17 + k] = tot[17 + k]; }
    }
}

// ---------------- main: one pass over x, MFMA 16x16x32 bf16 ----------------
// 256 blocks x 1024 threads; 16 waves/block; wave <-> one 16-row tile.
// A-frag (remapped): lane l (n=l&15, lc=l>>4), step s:
//   xa = x[n][s*32 + lc*4 .. +3]   -> regs j=0..3
//   xb = x[n][s*32 + 16 + lc*4 ..] -> regs j=4..7
// B-frag: gwb staged in LDS, read at ushort offset s*512 + lane*8.
// C: col = lane&15 (k), row = (lane>>4)*4 + reg  [m89-verified].
// K-loop is rotated per wave: s runs start..127 then 0..start-1.
__global__ __launch_bounds__(1024, 4) void hyp_main(
    const float* __restrict__ x, const unsigned short* __restrict__ gwb_g,
    const float* __restrict__ sc, float* __restrict__ out)
{
    __shared__ unsigned short gwb[ND * NK];  // 128 KB

    const int lane = threadIdx.x & 63;
    const int wid  = threadIdx.x >> 6;
    const int tile = (blockIdx.x << 4) + wid;   // 0..4095, one per wave
    const int lr = lane & 15;                   // A-row within tile / C-col (k)
    const int lc = lane >> 4;                   // lane group

    const float* xp = x + (size_t)(tile * 16 + lr) * ND + lc * 4;
    const unsigned short* lp = gwb + lane * 8;  // + s*512 ushorts per step
    const int start = (tile * 53) & 127;        // per-wave column rotation

    {
        const uint4* src = (const uint4*)gwb_g;
        uint4* dst = (uint4*)gwb;
#pragma unroll
        for (int i = 0; i < 8; ++i)
            dst[threadIdx.x + i * 1024] = src[threadIdx.x + i * 1024];
    }
    __syncthreads();

    // epilogue scalars: issue early, used late
    const float coef = sc[0];
    const float gk = sc[1 + lr];   // G[k], k = lane&15 = C-col
    const float bk = sc[17 + lr];  // B[k]

    f32x4 acc = {0.f, 0.f, 0.f, 0.f};
    float s1 = 0.f, s2 = 0.f;

#define PROCESS(SS) do {                                                  \
        f32x4 xa = *(const f32x4*)(xp + (SS) * 32);                       \
        f32x4 xb = *(const f32x4*)(xp + (SS) * 32 + 16);                  \
        bf16x8 afrag;                                                     \
        afrag[0] = (short)f2bf(xa[0]); afrag[1] = (short)f2bf(xa[1]);     \
        afrag[2] = (short)f2bf(xa[2]); afrag[3] = (short)f2bf(xa[3]);     \
        afrag[4] = (short)f2bf(xb[0]); afrag[5] = (short)f2bf(xb[1]);     \
        afrag[6] = (short)f2bf(xb[2]); afrag[7] = (short)f2bf(xb[3]);     \
        s1 += ((xa[0] + xa[1]) + (xa[2] + xa[3]))                         \
            + ((xb[0] + xb[1]) + (xb[2] + xb[3]));                        \
        s2 = fmaf(xa[0], xa[0], s2); s2 = fmaf(xa[1], xa[1], s2);         \
        s2 = fmaf(xa[2], xa[2], s2); s2 = fmaf(xa[3], xa[3], s2);         \
        s2 = fmaf(xb[0], xb[0], s2); s2 = fmaf(xb[1], xb[1], s2);         \
        s2 = fmaf(xb[2], xb[2], s2); s2 = fmaf(xb[3], xb[3], s2);         \
        bf16x8 bfrag = *(const bf16x8*)(lp + (SS) * 512);                 \
        acc = __builtin_amdgcn_mfma_f32_16x16x32_bf16(afrag, bfrag, acc, 0, 0, 0); \
    } while (0)

#pragma unroll 4
    for (int s = start; s < 128; ++s) PROCESS(s);
#pragma unroll 4
    for (int s = 0; s < start; ++s) PROCESS(s);
#undef PROCESS

    // S1/S2 for row lr: reduce across the 4 lanes {l, l^16, l^32, l^48}
    s1 += __shfl_xor(s1, 16); s1 += __shfl_xor(s1, 32);
    s2 += __shfl_xor(s2, 16); s2 += __shfl_xor(s2, 32);
    const float mean = s1 * (1.0f / ND);
    const float var  = s2 * (1.0f / ND) - mean * mean;
    const float rstd = rsqrtf(var + 1e-5f);

    float vout[4];
#pragma unroll
    for (int j = 0; j < 4; ++j) {
        const int r = lc * 4 + j;              // C-row within tile
        const float m_r  = __shfl(mean, r);    // stats live in lane r (r<16)
        const float rs_r = __shfl(rstd, r);
        vout[j] = coef * (fmaf(-m_r, gk, acc[j]) * rs_r + bk);
    }

    // row-norm over k: reduce across the 16 lanes sharing lc (xor masks 1,2,4,8)
    float nsq[4];
#pragma unroll
    for (int j = 0; j < 4; ++j) nsq[j] = vout[j] * vout[j];
#pragma unroll
    for (int m = 1; m < 16; m <<= 1) {
#pragma unroll
        for (int j = 0; j < 4; ++j) nsq[j] += __shfl_xor(nsq[j], m);
    }

#pragma unroll
    for (int j = 0; j < 4; ++j) {
        float nv = sqrtf(nsq[j]);
        nv = fmaxf(nv, 1e-15f);
        const float fac = tanhf(nv) / nv;
        out[(size_t)(tile * 16 + lc * 4 + j) * NK + lr] = vout[j] * fac;
    }
}

extern "C" void kernel_launch(void* const* d_in, const int* in_sizes, int n_in,
                              void* d_out, int out_size, void* d_ws, size_t ws_size,
                              hipStream_t stream) {
    const float* x     = (const float*)d_in[0];
    const float* gamma = (const float*)d_in[1];
    const float* beta  = (const float*)d_in[2];
    const float* W     = (const float*)d_in[3];
    const float* u     = (const float*)d_in[4];
    const float* ls    = (const float*)d_in[5];

    char* ws = (char*)d_ws;
    unsigned short* ws_gwb = (unsigned short*)(ws + GWB_OFF);
    float* ws_t    = (float*)(ws + T_OFF);
    float* ws_part = (float*)(ws + PART_OFF);
    float* sc      = (float*)(ws + SC_OFF);
    float* out     = (float*)d_out;

    prep_a<<<16, 256, 0, stream>>>(W, gamma, beta, u, ws_t, ws_gwb, ws_part);
    prep_b<<<1, 256, 0, stream>>>(W, ws_t, ws_part, ls, sc);
    hyp_main<<<256, 1024, 0, stream>>>(x, ws_gwb, sc, out);
}